// Round 11
// baseline (711.101 us; speedup 1.0000x reference)
//
#include <hip/hip_runtime.h>
#include <hip/hip_bf16.h>

#define NN 50000
#define NEDGE 800000
#define HD 256
#define ACT_LD 1280
#define NGRAPH 64
#define BN_EPS 1e-3f

#define BM 128
#define BN 128
#define BK 64          // shorts per LDS row (linear dest for global_load_lds)

#define SCAN_NBLK ((NN + 255) / 256)   // 196

using bf16 = __hip_bfloat16;
typedef __attribute__((ext_vector_type(8))) short bf16x8;  // 8 bf16 = 4 VGPR (MFMA A/B frag)
typedef __attribute__((ext_vector_type(4))) float f32x4;   // MFMA C/D frag

#define GLB(p) ((const __attribute__((address_space(1))) void*)(p))
#define LDS(p) ((__attribute__((address_space(3))) void*)(p))

static __device__ __forceinline__ float bf2f(unsigned short u) {
    union { float f; unsigned int i; } c;
    c.i = ((unsigned int)u) << 16;
    return c.f;
}
static __device__ __forceinline__ unsigned short f2bf(float f) {
    bf16 t = __float2bfloat16(f);   // round-to-nearest-even
    return *reinterpret_cast<unsigned short*>(&t);
}

// ---------------------------------------------------------------------------
// W (K x 256 fp32, row-major) -> Wt (256 x K bf16, row-major)  [32x32 LDS tiles]
// ---------------------------------------------------------------------------
__global__ __launch_bounds__(256)
void transpose_w(const float* __restrict__ W, bf16* __restrict__ Wt, int K)
{
    __shared__ unsigned short T[32][33];
    const int k0 = blockIdx.x * 32;
    const int n0 = blockIdx.y * 32;
#pragma unroll
    for (int i = 0; i < 4; ++i) {
        const int idx = threadIdx.x + i * 256;
        const int kk = idx >> 5, nn = idx & 31;
        T[kk][nn] = f2bf(W[(size_t)(k0 + kk) * HD + n0 + nn]);
    }
    __syncthreads();
#pragma unroll
    for (int i = 0; i < 4; ++i) {
        const int idx = threadIdx.x + i * 256;
        const int nn = idx >> 5, kk = idx & 31;
        unsigned short v = T[kk][nn];
        Wt[(size_t)(n0 + nn) * K + k0 + kk] = *reinterpret_cast<bf16*>(&v);
    }
}

// ---------------------------------------------------------------------------
// x (N x 128 fp32) -> xb (N x 128 bf16)
// ---------------------------------------------------------------------------
__global__ __launch_bounds__(256)
void convert_x(const float* __restrict__ x, bf16* __restrict__ xb)
{
    const int i = blockIdx.x * blockDim.x + threadIdx.x;   // over NN*32 float4s
    if (i >= NN * 32) return;
    const float4 v = *reinterpret_cast<const float4*>(x + (size_t)i * 4);
    ushort4 o;
    o.x = f2bf(v.x); o.y = f2bf(v.y); o.z = f2bf(v.z); o.w = f2bf(v.w);
    *reinterpret_cast<ushort4*>((unsigned short*)xb + (size_t)i * 4) = o;
}

// ---------------------------------------------------------------------------
// MFMA GEMM + BN + PReLU:  out = prelu(bn(A @ W + b))
// 128x128 tile, BK=64, 4 waves (2x2).
// 2-phase double-buffered prefetch: global_load_lds of tile t+1 stays in
// flight across the barrier (counted vmcnt(8), never 0 mid-loop).
// XOR chunk-swizzle: LDS[r][c] = global[r][c ^ (r&7)] via pre-swizzled
// SOURCE address (gload_lds dest is linear); ds_read applies the same XOR.
// 16-way bank conflict -> 2-way (free).
// ---------------------------------------------------------------------------
__global__ __launch_bounds__(256)
void gemm_bn_act(const bf16* __restrict__ A, int lda,
                 const bf16* __restrict__ Wt, int K,
                 const float* __restrict__ bias,
                 const float* __restrict__ bn,
                 const float* __restrict__ alpha,
                 bf16* __restrict__ out, int ldo, int M)
{
    __shared__ short As0[BM * BK];   // 16 KB each, linear [row][64]
    __shared__ short Bs0[BN * BK];
    __shared__ short As1[BM * BK];
    __shared__ short Bs1[BN * BK];

    const int tid  = threadIdx.x;
    const int wid  = tid >> 6;
    const int lane = tid & 63;
    const int lo   = lane & 15;
    const int hi   = lane >> 4;
    const int wr   = wid >> 1;    // wave row 0..1
    const int wc   = wid & 1;     // wave col 0..1

    const int m0 = blockIdx.x * BM;
    const int n0 = blockIdx.y * BN;

    // staging lane geometry: lane -> dest (row srow, chunk schk) of an 8-row group;
    // source chunk is XOR-swizzled so linear LDS == swizzled tile.
    const int srow = lane >> 3;                  // 0..7 row within group
    const int ssel = ((lane & 7) ^ srow) * 8;    // swizzled source elem offset (chunk^row&7)*8

    const int nt = K / BK;

    f32x4 acc[4][4] = {};   // [row-tile][col-tile]

#define STAGE_T(BUFA, BUFB, kt) do {                                                     \
    const int kk0 = (kt) * BK;                                                           \
    _Pragma("unroll")                                                                    \
    for (int i_ = 0; i_ < 4; ++i_) {                                                     \
        const int grp = wid * 4 + i_;                                                    \
        const int row = grp * 8 + srow;                                                  \
        const int ar  = (m0 + row < M) ? (m0 + row) : (M - 1);                           \
        __builtin_amdgcn_global_load_lds(GLB(A + (size_t)ar * lda + kk0 + ssel),         \
                                         LDS(&BUFA[grp * 8 * BK]), 16, 0, 0);            \
        __builtin_amdgcn_global_load_lds(GLB(Wt + (size_t)(n0 + row) * K + kk0 + ssel),  \
                                         LDS(&BUFB[grp * 8 * BK]), 16, 0, 0);            \
    } } while (0)

#define COMPUTE_T(BUFA, BUFB) do {                                                       \
    _Pragma("unroll")                                                                    \
    for (int kc = 0; kc < 2; ++kc) {                                                     \
        bf16x8 af[4], bfr[4];                                                            \
        _Pragma("unroll")                                                                \
        for (int rt = 0; rt < 4; ++rt) {                                                 \
            const int row = wr * 64 + rt * 16 + lo;                                      \
            const int ch  = (kc * 4 + hi) ^ (row & 7);                                   \
            af[rt] = *reinterpret_cast<const bf16x8*>(&BUFA[row * BK + ch * 8]);         \
        }                                                                                \
        _Pragma("unroll")                                                                \
        for (int ct = 0; ct < 4; ++ct) {                                                 \
            const int rowb = wc * 64 + ct * 16 + lo;                                     \
            const int chb  = (kc * 4 + hi) ^ (rowb & 7);                                 \
            bfr[ct] = *reinterpret_cast<const bf16x8*>(&BUFB[rowb * BK + chb * 8]);      \
        }                                                                                \
        _Pragma("unroll")                                                                \
        for (int rt = 0; rt < 4; ++rt)                                                   \
            _Pragma("unroll")                                                            \
            for (int ct = 0; ct < 4; ++ct)                                               \
                acc[rt][ct] = __builtin_amdgcn_mfma_f32_16x16x32_bf16(af[rt], bfr[ct],   \
                                                                     acc[rt][ct], 0, 0, 0); \
    } } while (0)

    STAGE_T(As0, Bs0, 0);
    int t = 0;
    while (t < nt) {
        // phase A: prefetch t+1 into buf1, compute buf0
        if (t + 1 < nt) {
            STAGE_T(As1, Bs1, t + 1);
            asm volatile("s_waitcnt vmcnt(8)" ::: "memory");   // tile t landed; t+1 in flight
        } else {
            asm volatile("s_waitcnt vmcnt(0)" ::: "memory");
        }
        __builtin_amdgcn_s_barrier();
        __builtin_amdgcn_sched_barrier(0);
        COMPUTE_T(As0, Bs0);
        __builtin_amdgcn_s_barrier();          // all reads of buf0 done before next overwrite
        __builtin_amdgcn_sched_barrier(0);
        ++t;
        if (t >= nt) break;
        // phase B: prefetch t+1 into buf0, compute buf1
        if (t + 1 < nt) {
            STAGE_T(As0, Bs0, t + 1);
            asm volatile("s_waitcnt vmcnt(8)" ::: "memory");
        } else {
            asm volatile("s_waitcnt vmcnt(0)" ::: "memory");
        }
        __builtin_amdgcn_s_barrier();
        __builtin_amdgcn_sched_barrier(0);
        COMPUTE_T(As1, Bs1);
        __builtin_amdgcn_s_barrier();
        __builtin_amdgcn_sched_barrier(0);
        ++t;
    }
#undef STAGE_T
#undef COMPUTE_T

    // epilogue: bn + prelu per column, scattered bf16 stores
    float sc[4], sh[4], al[4];
#pragma unroll
    for (int ct = 0; ct < 4; ++ct) {
        const int c = n0 + wc * 64 + ct * 16 + lo;
        const float g  = bn[c];
        const float be = bn[HD + c];
        const float mu = bn[2 * HD + c];
        const float va = bn[3 * HD + c];
        sc[ct] = g * rsqrtf(va + BN_EPS);
        sh[ct] = be + (bias[c] - mu) * sc[ct];
        al[ct] = alpha ? alpha[c] : 1.0f;
    }
#pragma unroll
    for (int rt = 0; rt < 4; ++rt) {
#pragma unroll
        for (int i = 0; i < 4; ++i) {
            const int r = m0 + wr * 64 + rt * 16 + hi * 4 + i;
            if (r >= M) continue;
#pragma unroll
            for (int ct = 0; ct < 4; ++ct) {
                float v = acc[rt][ct][i] * sc[ct] + sh[ct];
                v = (v >= 0.f) ? v : al[ct] * v;
                unsigned short u = f2bf(v);
                out[(size_t)r * ldo + n0 + wc * 64 + ct * 16 + lo] = *reinterpret_cast<bf16*>(&u);
            }
        }
    }
}

// ---------------------------------------------------------------------------
// CSR build: histogram, 3-stage parallel scan, fill edge list.
// ---------------------------------------------------------------------------
__global__ __launch_bounds__(256)
void hist_tgt(const int* __restrict__ edge, int* __restrict__ ecnt)
{
    const int e = blockIdx.x * blockDim.x + threadIdx.x;
    if (e >= NEDGE) return;
    atomicAdd(&ecnt[edge[2 * e]], 1);
}

__global__ __launch_bounds__(256)
void block_sums(const int* __restrict__ ecnt, int* __restrict__ bsum)
{
    __shared__ int red[256];
    const int t = threadIdx.x;
    const int idx = blockIdx.x * 256 + t;
    red[t] = (idx < NN) ? ecnt[idx] : 0;
    __syncthreads();
#pragma unroll
    for (int d = 128; d > 0; d >>= 1) {
        if (t < d) red[t] += red[t + d];
        __syncthreads();
    }
    if (t == 0) bsum[blockIdx.x] = red[0];
}

__global__ __launch_bounds__(256)
void scan_bsums(const int* __restrict__ bsum, int* __restrict__ bbase,
                int* __restrict__ off)
{
    __shared__ int s[256];
    const int t = threadIdx.x;
    s[t] = (t < SCAN_NBLK) ? bsum[t] : 0;
    __syncthreads();
    for (int d = 1; d < 256; d <<= 1) {
        const int v = (t >= d) ? s[t - d] : 0;
        __syncthreads();
        s[t] += v;
        __syncthreads();
    }
    if (t < SCAN_NBLK) bbase[t] = (t == 0) ? 0 : s[t - 1];
    if (t == 255) off[NN] = s[255];   // total = NEDGE
}

__global__ __launch_bounds__(256)
void block_scan(const int* __restrict__ ecnt, const int* __restrict__ bbase,
                int* __restrict__ off, int* __restrict__ cursor)
{
    __shared__ int s[256];
    const int t = threadIdx.x;
    const int idx = blockIdx.x * 256 + t;
    const int v = (idx < NN) ? ecnt[idx] : 0;
    s[t] = v;
    __syncthreads();
    for (int d = 1; d < 256; d <<= 1) {
        const int x = (t >= d) ? s[t - d] : 0;
        __syncthreads();
        s[t] += x;
        __syncthreads();
    }
    if (idx < NN) {
        const int excl = bbase[blockIdx.x] + s[t] - v;   // exclusive prefix
        off[idx] = excl;
        cursor[idx] = excl;
    }
}

__global__ __launch_bounds__(256)
void fill_elist(const int* __restrict__ edge,
                int* __restrict__ cursor, int* __restrict__ elist)
{
    const int e = blockIdx.x * blockDim.x + threadIdx.x;
    if (e >= NEDGE) return;
    const int tgt = edge[2 * e + 0];
    const int src = edge[2 * e + 1];
    const int pos = atomicAdd(&cursor[tgt], 1);
    elist[pos] = src;
}

// ---------------------------------------------------------------------------
// Atomic-free gather with x4 ILP unroll (4 row-loads in flight per wave).
// ---------------------------------------------------------------------------
__global__ __launch_bounds__(256)
void gather_nodes(const bf16* __restrict__ h,
                  const int* __restrict__ off,
                  const int* __restrict__ elist,
                  bf16* __restrict__ dst)
{
    const int node = blockIdx.x * 4 + (threadIdx.x >> 6);
    if (node >= NN) return;
    const int lane = threadIdx.x & 63;
    const int j0 = off[node];
    const int j1 = off[node + 1];

    float4 a0 = make_float4(0.f, 0.f, 0.f, 0.f);
    float4 a1 = make_float4(0.f, 0.f, 0.f, 0.f);
    float4 a2 = make_float4(0.f, 0.f, 0.f, 0.f);
    float4 a3 = make_float4(0.f, 0.f, 0.f, 0.f);

    int j = j0;
    for (; j + 4 <= j1; j += 4) {
        const int s0 = elist[j + 0];
        const int s1 = elist[j + 1];
        const int s2 = elist[j + 2];
        const int s3 = elist[j + 3];
        const ushort4 u0 = *reinterpret_cast<const ushort4*>(h + (size_t)s0 * HD + lane * 4);
        const ushort4 u1 = *reinterpret_cast<const ushort4*>(h + (size_t)s1 * HD + lane * 4);
        const ushort4 u2 = *reinterpret_cast<const ushort4*>(h + (size_t)s2 * HD + lane * 4);
        const ushort4 u3 = *reinterpret_cast<const ushort4*>(h + (size_t)s3 * HD + lane * 4);
        a0.x += bf2f(u0.x); a0.y += bf2f(u0.y); a0.z += bf2f(u0.z); a0.w += bf2f(u0.w);
        a1.x += bf2f(u1.x); a1.y += bf2f(u1.y); a1.z += bf2f(u1.z); a1.w += bf2f(u1.w);
        a2.x += bf2f(u2.x); a2.y += bf2f(u2.y); a2.z += bf2f(u2.z); a2.w += bf2f(u2.w);
        a3.x += bf2f(u3.x); a3.y += bf2f(u3.y); a3.z += bf2f(u3.z); a3.w += bf2f(u3.w);
    }
    for (; j < j1; ++j) {
        const int s0 = elist[j];
        const ushort4 u0 = *reinterpret_cast<const ushort4*>(h + (size_t)s0 * HD + lane * 4);
        a0.x += bf2f(u0.x); a0.y += bf2f(u0.y); a0.z += bf2f(u0.z); a0.w += bf2f(u0.w);
    }

    const float rx = (a0.x + a1.x) + (a2.x + a3.x);
    const float ry = (a0.y + a1.y) + (a2.y + a3.y);
    const float rz = (a0.z + a1.z) + (a2.z + a3.z);
    const float rw = (a0.w + a1.w) + (a2.w + a3.w);

    ushort4 o;
    o.x = f2bf(rx); o.y = f2bf(ry); o.z = f2bf(rz); o.w = f2bf(rw);
    *reinterpret_cast<ushort4*>(dst + (size_t)node * ACT_LD + lane * 4) = o;
}

// ---------------------------------------------------------------------------
// post1 (256->1 dense + bn) fused with graph segment-sum (hierarchical).
// ---------------------------------------------------------------------------
__global__ __launch_bounds__(256)
void post1_segsum(const bf16* __restrict__ h,
                  const float* __restrict__ W,
                  const float* __restrict__ b,
                  const float* __restrict__ bn,
                  const int* __restrict__ seg,
                  float* __restrict__ outg)
{
    __shared__ float bins[NGRAPH];
    const int t = threadIdx.x;
    if (t < NGRAPH) bins[t] = 0.f;
    __syncthreads();

    const int wave = t >> 6;
    const int lane = t & 63;
    const float4 wv = *reinterpret_cast<const float4*>(W + lane * 4);
    const float g = bn[0], be = bn[1], mu = bn[2], va = bn[3];
    const float bscale = g * rsqrtf(va + BN_EPS);
    const float b0 = b[0];

    const int row0 = blockIdx.x * 64 + wave * 16;
#pragma unroll
    for (int i = 0; i < 16; ++i) {
        const int row = row0 + i;
        if (row >= NN) break;
        const ushort4 u = *reinterpret_cast<const ushort4*>(h + (size_t)row * HD + lane * 4);
        float s = bf2f(u.x) * wv.x + bf2f(u.y) * wv.y + bf2f(u.z) * wv.z + bf2f(u.w) * wv.w;
#pragma unroll
        for (int off = 32; off > 0; off >>= 1) s += __shfl_down(s, off);
        if (lane == 0) {
            const float y = bscale * (s + b0 - mu) + be;
            atomicAdd(&bins[seg[row]], y);
        }
    }
    __syncthreads();
    if (t < NGRAPH && bins[t] != 0.f) atomicAdd(&outg[t], bins[t]);
}

// ---------------------------------------------------------------------------
extern "C" void kernel_launch(void* const* d_in, const int* in_sizes, int n_in,
                              void* d_out, int out_size, void* d_ws, size_t ws_size,
                              hipStream_t stream)
{
    const float* x    = (const float*)d_in[0];
    const int*   edge = (const int*)d_in[1];
    const int*   seg  = (const int*)d_in[2];

    const float* Wsrc[7], *bi[7], *bnp[7], *ap[7];
    for (int L = 0; L < 7; ++L) {
        Wsrc[L] = (const float*)d_in[4 + 4 * L + 0];
        bi[L]   = (const float*)d_in[4 + 4 * L + 1];
        bnp[L]  = (const float*)d_in[4 + 4 * L + 2];
        ap[L]   = (const float*)d_in[4 + 4 * L + 3];
    }
    const float* post1_W  = (const float*)d_in[32];
    const float* post1_b  = (const float*)d_in[33];
    const float* post1_bn = (const float*)d_in[34];

    static const int Ks[7] = {128, 256, 256, 512, 768, 1024, 1280};

    // Workspace (~172 MB):
    bf16* act  = (bf16*)d_ws;                          // 128.0 MB
    bf16* h    = act + (size_t)NN * ACT_LD;            //  25.6 MB
    bf16* xb   = h + (size_t)NN * HD;                  //  12.8 MB
    bf16* wt0  = xb + (size_t)NN * 128;                //   2.16 MB total Wt
    bf16* WtB[7];
    {
        size_t o = 0;
        for (int L = 0; L < 7; ++L) { WtB[L] = wt0 + o; o += (size_t)Ks[L] * HD; }
    }
    int* ecnt   = (int*)(wt0 + (size_t)4224 * HD);
    int* off    = ecnt + NN;
    int* cursor = off + NN + 1;
    int* elist  = cursor + NN;
    int* bsum   = elist + NEDGE;
    int* bbase  = bsum + SCAN_NBLK;

    hipMemsetAsync(d_out, 0, (size_t)out_size * sizeof(float), stream);
    hipMemsetAsync(ecnt, 0, NN * sizeof(int), stream);

    const dim3 blk(256);
    const dim3 gemm_grid((NN + BM - 1) / BM, HD / BN);   // (391, 2)
    const int  edge_grid = (NEDGE + 255) / 256;
    const int  node_grid = (NN + 3) / 4;

    // weight transposes (fp32 KxH -> bf16 HxK) + x conversion
    for (int L = 0; L < 7; ++L)
        transpose_w<<<dim3(Ks[L] / 32, HD / 32), blk, 0, stream>>>(Wsrc[L], WtB[L], Ks[L]);
    convert_x<<<(NN * 32 + 255) / 256, blk, 0, stream>>>(x, xb);

    // CSR build (reused by all 4 gconv layers)
    hist_tgt<<<edge_grid, blk, 0, stream>>>(edge, ecnt);
    block_sums<<<SCAN_NBLK, blk, 0, stream>>>(ecnt, bsum);
    scan_bsums<<<1, blk, 0, stream>>>(bsum, bbase, off);
    block_scan<<<SCAN_NBLK, blk, 0, stream>>>(ecnt, bbase, off, cursor);
    fill_elist<<<edge_grid, blk, 0, stream>>>(edge, cursor, elist);

    // pre0: xb(K=128) -> h
    gemm_bn_act<<<gemm_grid, blk, 0, stream>>>(xb, 128, WtB[0], 128, bi[0], bnp[0], ap[0], h, HD, NN);
    // pre1: h(K=256) -> act[:,1024:1280) (= out1)
    gemm_bn_act<<<gemm_grid, blk, 0, stream>>>(h, HD, WtB[1], 256, bi[1], bnp[1], ap[1], act + 1024, ACT_LD, NN);

    // gconv layers: input = act cols [1024-256L, 1280), K = 256*(L+1)
    for (int L = 0; L < 4; ++L) {
        const int in_off = 1024 - 256 * L;
        const int K      = 256 * (L + 1);
        gemm_bn_act<<<gemm_grid, blk, 0, stream>>>(act + in_off, ACT_LD, WtB[2 + L], K, bi[2 + L], bnp[2 + L], ap[2 + L], h, HD, NN);
        gather_nodes<<<node_grid, blk, 0, stream>>>(h, off, elist, act + (in_off - 256));
    }

    // post0: act(K=1280) -> h
    gemm_bn_act<<<gemm_grid, blk, 0, stream>>>(act, ACT_LD, WtB[6], 1280, bi[6], bnp[6], ap[6], h, HD, NN);
    // post1 + segment-sum -> d_out (64 floats)
    post1_segsum<<<(NN + 63) / 64, blk, 0, stream>>>(h, post1_W, post1_b, post1_bn, seg, (float*)d_out);
}

// Round 12
// 592.955 us; speedup vs baseline: 1.1993x; 1.1993x over previous
//
#include <hip/hip_runtime.h>
#include <hip/hip_bf16.h>

#define NN 50000
#define NEDGE 800000
#define HD 256
#define ACT_LD 1280
#define NGRAPH 64
#define BN_EPS 1e-3f

#define BM 128
#define BN 128
#define BK 64          // shorts per LDS row (linear dest for global_load_lds)

#define SCAN_NBLK ((NN + 255) / 256)   // 196

using bf16 = __hip_bfloat16;
typedef __attribute__((ext_vector_type(8))) short bf16x8;  // 8 bf16 = 4 VGPR (MFMA A/B frag)
typedef __attribute__((ext_vector_type(4))) float f32x4;   // MFMA C/D frag

#define GLB(p) ((const __attribute__((address_space(1))) void*)(p))
#define LDS(p) ((__attribute__((address_space(3))) void*)(p))

static __device__ __forceinline__ float bf2f(unsigned short u) {
    union { float f; unsigned int i; } c;
    c.i = ((unsigned int)u) << 16;
    return c.f;
}
static __device__ __forceinline__ unsigned short f2bf(float f) {
    bf16 t = __float2bfloat16(f);   // round-to-nearest-even
    return *reinterpret_cast<unsigned short*>(&t);
}

// ---------------------------------------------------------------------------
// W (K x 256 fp32, row-major) -> Wt (256 x K bf16, row-major)  [32x32 LDS tiles]
// ---------------------------------------------------------------------------
__global__ __launch_bounds__(256)
void transpose_w(const float* __restrict__ W, bf16* __restrict__ Wt, int K)
{
    __shared__ unsigned short T[32][33];
    const int k0 = blockIdx.x * 32;
    const int n0 = blockIdx.y * 32;
#pragma unroll
    for (int i = 0; i < 4; ++i) {
        const int idx = threadIdx.x + i * 256;
        const int kk = idx >> 5, nn = idx & 31;
        T[kk][nn] = f2bf(W[(size_t)(k0 + kk) * HD + n0 + nn]);
    }
    __syncthreads();
#pragma unroll
    for (int i = 0; i < 4; ++i) {
        const int idx = threadIdx.x + i * 256;
        const int nn = idx >> 5, kk = idx & 31;
        unsigned short v = T[kk][nn];
        Wt[(size_t)(n0 + nn) * K + k0 + kk] = *reinterpret_cast<bf16*>(&v);
    }
}

// ---------------------------------------------------------------------------
// x (N x 128 fp32) -> xb (N x 128 bf16)
// ---------------------------------------------------------------------------
__global__ __launch_bounds__(256)
void convert_x(const float* __restrict__ x, bf16* __restrict__ xb)
{
    const int i = blockIdx.x * blockDim.x + threadIdx.x;   // over NN*32 float4s
    if (i >= NN * 32) return;
    const float4 v = *reinterpret_cast<const float4*>(x + (size_t)i * 4);
    ushort4 o;
    o.x = f2bf(v.x); o.y = f2bf(v.y); o.z = f2bf(v.z); o.w = f2bf(v.w);
    *reinterpret_cast<ushort4*>((unsigned short*)xb + (size_t)i * 4) = o;
}

// ---------------------------------------------------------------------------
// MFMA GEMM + BN + PReLU:  out = prelu(bn(A @ W + b))
// 128x128 tile, BK=64, 4 waves (2x2); single-buffer m97 schedule (32 KB LDS,
// occupancy-preserving) + XOR chunk-swizzle from R11 (verified: conflicts->0):
// LDS[r][c] = global[r][c ^ (r&7)] via pre-swizzled SOURCE (gload_lds dest is
// linear); ds_read applies the same XOR. Both-sides involution (rule #21).
// ---------------------------------------------------------------------------
__global__ __launch_bounds__(256)
void gemm_bn_act(const bf16* __restrict__ A, int lda,
                 const bf16* __restrict__ Wt, int K,
                 const float* __restrict__ bias,
                 const float* __restrict__ bn,
                 const float* __restrict__ alpha,
                 bf16* __restrict__ out, int ldo, int M)
{
    __shared__ short As[BM * BK];   // 16 KB, linear [row][64]
    __shared__ short Bs[BN * BK];   // 16 KB

    const int tid  = threadIdx.x;
    const int wid  = tid >> 6;
    const int lane = tid & 63;
    const int lo   = lane & 15;
    const int hi   = lane >> 4;
    const int wr   = wid >> 1;    // wave row 0..1
    const int wc   = wid & 1;     // wave col 0..1

    const int m0 = blockIdx.x * BM;
    const int n0 = blockIdx.y * BN;

    // staging: lane -> (row srow, swizzled source chunk). Linear LDS dest ==
    // swizzled tile content; ds_read un-swizzles with the same XOR.
    const int srow = lane >> 3;                  // 0..7 row within group
    const int ssel = ((lane & 7) ^ srow) * 8;    // (chunk ^ row&7) * 8 elems

    f32x4 acc[4][4] = {};   // [row-tile][col-tile]

    for (int k0 = 0; k0 < K; k0 += BK) {
        __syncthreads();   // previous iter's ds_reads done before overwrite
#pragma unroll
        for (int i = 0; i < 4; ++i) {
            const int grp = wid * 4 + i;              // 8-row group 0..15
            const int row = grp * 8 + srow;
            const int ar  = (m0 + row < M) ? (m0 + row) : (M - 1);   // clamp: dead rows never stored
            __builtin_amdgcn_global_load_lds(GLB(A + (size_t)ar * lda + k0 + ssel),
                                             LDS(&As[grp * 8 * BK]), 16, 0, 0);
            __builtin_amdgcn_global_load_lds(GLB(Wt + (size_t)(n0 + row) * K + k0 + ssel),
                                             LDS(&Bs[grp * 8 * BK]), 16, 0, 0);
        }
        __syncthreads();   // compiler drains vmcnt(0) before barrier -> LDS ready

#pragma unroll
        for (int kc = 0; kc < 2; ++kc) {       // two K=32 chunks
            bf16x8 af[4], bfr[4];
#pragma unroll
            for (int rt = 0; rt < 4; ++rt) {
                const int row = wr * 64 + rt * 16 + lo;
                const int ch  = (kc * 4 + hi) ^ (row & 7);
                af[rt] = *reinterpret_cast<const bf16x8*>(&As[row * BK + ch * 8]);
            }
#pragma unroll
            for (int ct = 0; ct < 4; ++ct) {
                const int rowb = wc * 64 + ct * 16 + lo;
                const int chb  = (kc * 4 + hi) ^ (rowb & 7);
                bfr[ct] = *reinterpret_cast<const bf16x8*>(&Bs[rowb * BK + chb * 8]);
            }
#pragma unroll
            for (int rt = 0; rt < 4; ++rt)
#pragma unroll
                for (int ct = 0; ct < 4; ++ct)
                    acc[rt][ct] = __builtin_amdgcn_mfma_f32_16x16x32_bf16(af[rt], bfr[ct], acc[rt][ct], 0, 0, 0);
        }
    }

    // epilogue: bn + prelu per column, scattered bf16 stores
    float sc[4], sh[4], al[4];
#pragma unroll
    for (int ct = 0; ct < 4; ++ct) {
        const int c = n0 + wc * 64 + ct * 16 + lo;
        const float g  = bn[c];
        const float be = bn[HD + c];
        const float mu = bn[2 * HD + c];
        const float va = bn[3 * HD + c];
        sc[ct] = g * rsqrtf(va + BN_EPS);
        sh[ct] = be + (bias[c] - mu) * sc[ct];
        al[ct] = alpha ? alpha[c] : 1.0f;
    }
#pragma unroll
    for (int rt = 0; rt < 4; ++rt) {
#pragma unroll
        for (int i = 0; i < 4; ++i) {
            const int r = m0 + wr * 64 + rt * 16 + hi * 4 + i;
            if (r >= M) continue;
#pragma unroll
            for (int ct = 0; ct < 4; ++ct) {
                float v = acc[rt][ct][i] * sc[ct] + sh[ct];
                v = (v >= 0.f) ? v : al[ct] * v;
                unsigned short u = f2bf(v);
                out[(size_t)r * ldo + n0 + wc * 64 + ct * 16 + lo] = *reinterpret_cast<bf16*>(&u);
            }
        }
    }
}

// ---------------------------------------------------------------------------
// CSR build: histogram, 3-stage parallel scan, fill edge list.
// ---------------------------------------------------------------------------
__global__ __launch_bounds__(256)
void hist_tgt(const int* __restrict__ edge, int* __restrict__ ecnt)
{
    const int e = blockIdx.x * blockDim.x + threadIdx.x;
    if (e >= NEDGE) return;
    atomicAdd(&ecnt[edge[2 * e]], 1);
}

__global__ __launch_bounds__(256)
void block_sums(const int* __restrict__ ecnt, int* __restrict__ bsum)
{
    __shared__ int red[256];
    const int t = threadIdx.x;
    const int idx = blockIdx.x * 256 + t;
    red[t] = (idx < NN) ? ecnt[idx] : 0;
    __syncthreads();
#pragma unroll
    for (int d = 128; d > 0; d >>= 1) {
        if (t < d) red[t] += red[t + d];
        __syncthreads();
    }
    if (t == 0) bsum[blockIdx.x] = red[0];
}

__global__ __launch_bounds__(256)
void scan_bsums(const int* __restrict__ bsum, int* __restrict__ bbase,
                int* __restrict__ off)
{
    __shared__ int s[256];
    const int t = threadIdx.x;
    s[t] = (t < SCAN_NBLK) ? bsum[t] : 0;
    __syncthreads();
    for (int d = 1; d < 256; d <<= 1) {
        const int v = (t >= d) ? s[t - d] : 0;
        __syncthreads();
        s[t] += v;
        __syncthreads();
    }
    if (t < SCAN_NBLK) bbase[t] = (t == 0) ? 0 : s[t - 1];
    if (t == 255) off[NN] = s[255];   // total = NEDGE
}

__global__ __launch_bounds__(256)
void block_scan(const int* __restrict__ ecnt, const int* __restrict__ bbase,
                int* __restrict__ off, int* __restrict__ cursor)
{
    __shared__ int s[256];
    const int t = threadIdx.x;
    const int idx = blockIdx.x * 256 + t;
    const int v = (idx < NN) ? ecnt[idx] : 0;
    s[t] = v;
    __syncthreads();
    for (int d = 1; d < 256; d <<= 1) {
        const int x = (t >= d) ? s[t - d] : 0;
        __syncthreads();
        s[t] += x;
        __syncthreads();
    }
    if (idx < NN) {
        const int excl = bbase[blockIdx.x] + s[t] - v;   // exclusive prefix
        off[idx] = excl;
        cursor[idx] = excl;
    }
}

__global__ __launch_bounds__(256)
void fill_elist(const int* __restrict__ edge,
                int* __restrict__ cursor, int* __restrict__ elist)
{
    const int e = blockIdx.x * blockDim.x + threadIdx.x;
    if (e >= NEDGE) return;
    const int tgt = edge[2 * e + 0];
    const int src = edge[2 * e + 1];
    const int pos = atomicAdd(&cursor[tgt], 1);
    elist[pos] = src;
}

// ---------------------------------------------------------------------------
// Atomic-free gather with x4 ILP unroll (4 row-loads in flight per wave).
// ---------------------------------------------------------------------------
__global__ __launch_bounds__(256)
void gather_nodes(const bf16* __restrict__ h,
                  const int* __restrict__ off,
                  const int* __restrict__ elist,
                  bf16* __restrict__ dst)
{
    const int node = blockIdx.x * 4 + (threadIdx.x >> 6);
    if (node >= NN) return;
    const int lane = threadIdx.x & 63;
    const int j0 = off[node];
    const int j1 = off[node + 1];

    float4 a0 = make_float4(0.f, 0.f, 0.f, 0.f);
    float4 a1 = make_float4(0.f, 0.f, 0.f, 0.f);
    float4 a2 = make_float4(0.f, 0.f, 0.f, 0.f);
    float4 a3 = make_float4(0.f, 0.f, 0.f, 0.f);

    int j = j0;
    for (; j + 4 <= j1; j += 4) {
        const int s0 = elist[j + 0];
        const int s1 = elist[j + 1];
        const int s2 = elist[j + 2];
        const int s3 = elist[j + 3];
        const ushort4 u0 = *reinterpret_cast<const ushort4*>(h + (size_t)s0 * HD + lane * 4);
        const ushort4 u1 = *reinterpret_cast<const ushort4*>(h + (size_t)s1 * HD + lane * 4);
        const ushort4 u2 = *reinterpret_cast<const ushort4*>(h + (size_t)s2 * HD + lane * 4);
        const ushort4 u3 = *reinterpret_cast<const ushort4*>(h + (size_t)s3 * HD + lane * 4);
        a0.x += bf2f(u0.x); a0.y += bf2f(u0.y); a0.z += bf2f(u0.z); a0.w += bf2f(u0.w);
        a1.x += bf2f(u1.x); a1.y += bf2f(u1.y); a1.z += bf2f(u1.z); a1.w += bf2f(u1.w);
        a2.x += bf2f(u2.x); a2.y += bf2f(u2.y); a2.z += bf2f(u2.z); a2.w += bf2f(u2.w);
        a3.x += bf2f(u3.x); a3.y += bf2f(u3.y); a3.z += bf2f(u3.z); a3.w += bf2f(u3.w);
    }
    for (; j < j1; ++j) {
        const int s0 = elist[j];
        const ushort4 u0 = *reinterpret_cast<const ushort4*>(h + (size_t)s0 * HD + lane * 4);
        a0.x += bf2f(u0.x); a0.y += bf2f(u0.y); a0.z += bf2f(u0.z); a0.w += bf2f(u0.w);
    }

    const float rx = (a0.x + a1.x) + (a2.x + a3.x);
    const float ry = (a0.y + a1.y) + (a2.y + a3.y);
    const float rz = (a0.z + a1.z) + (a2.z + a3.z);
    const float rw = (a0.w + a1.w) + (a2.w + a3.w);

    ushort4 o;
    o.x = f2bf(rx); o.y = f2bf(ry); o.z = f2bf(rz); o.w = f2bf(rw);
    *reinterpret_cast<ushort4*>(dst + (size_t)node * ACT_LD + lane * 4) = o;
}

// ---------------------------------------------------------------------------
// post1 (256->1 dense + bn) fused with graph segment-sum (hierarchical).
// ---------------------------------------------------------------------------
__global__ __launch_bounds__(256)
void post1_segsum(const bf16* __restrict__ h,
                  const float* __restrict__ W,
                  const float* __restrict__ b,
                  const float* __restrict__ bn,
                  const int* __restrict__ seg,
                  float* __restrict__ outg)
{
    __shared__ float bins[NGRAPH];
    const int t = threadIdx.x;
    if (t < NGRAPH) bins[t] = 0.f;
    __syncthreads();

    const int wave = t >> 6;
    const int lane = t & 63;
    const float4 wv = *reinterpret_cast<const float4*>(W + lane * 4);
    const float g = bn[0], be = bn[1], mu = bn[2], va = bn[3];
    const float bscale = g * rsqrtf(va + BN_EPS);
    const float b0 = b[0];

    const int row0 = blockIdx.x * 64 + wave * 16;
#pragma unroll
    for (int i = 0; i < 16; ++i) {
        const int row = row0 + i;
        if (row >= NN) break;
        const ushort4 u = *reinterpret_cast<const ushort4*>(h + (size_t)row * HD + lane * 4);
        float s = bf2f(u.x) * wv.x + bf2f(u.y) * wv.y + bf2f(u.z) * wv.z + bf2f(u.w) * wv.w;
#pragma unroll
        for (int off = 32; off > 0; off >>= 1) s += __shfl_down(s, off);
        if (lane == 0) {
            const float y = bscale * (s + b0 - mu) + be;
            atomicAdd(&bins[seg[row]], y);
        }
    }
    __syncthreads();
    if (t < NGRAPH && bins[t] != 0.f) atomicAdd(&outg[t], bins[t]);
}

// ---------------------------------------------------------------------------
extern "C" void kernel_launch(void* const* d_in, const int* in_sizes, int n_in,
                              void* d_out, int out_size, void* d_ws, size_t ws_size,
                              hipStream_t stream)
{
    const float* x    = (const float*)d_in[0];
    const int*   edge = (const int*)d_in[1];
    const int*   seg  = (const int*)d_in[2];

    const float* Wsrc[7], *bi[7], *bnp[7], *ap[7];
    for (int L = 0; L < 7; ++L) {
        Wsrc[L] = (const float*)d_in[4 + 4 * L + 0];
        bi[L]   = (const float*)d_in[4 + 4 * L + 1];
        bnp[L]  = (const float*)d_in[4 + 4 * L + 2];
        ap[L]   = (const float*)d_in[4 + 4 * L + 3];
    }
    const float* post1_W  = (const float*)d_in[32];
    const float* post1_b  = (const float*)d_in[33];
    const float* post1_bn = (const float*)d_in[34];

    static const int Ks[7] = {128, 256, 256, 512, 768, 1024, 1280};

    // Workspace (~172 MB):
    bf16* act  = (bf16*)d_ws;                          // 128.0 MB
    bf16* h    = act + (size_t)NN * ACT_LD;            //  25.6 MB
    bf16* xb   = h + (size_t)NN * HD;                  //  12.8 MB
    bf16* wt0  = xb + (size_t)NN * 128;                //   2.16 MB total Wt
    bf16* WtB[7];
    {
        size_t o = 0;
        for (int L = 0; L < 7; ++L) { WtB[L] = wt0 + o; o += (size_t)Ks[L] * HD; }
    }
    int* ecnt   = (int*)(wt0 + (size_t)4224 * HD);
    int* off    = ecnt + NN;
    int* cursor = off + NN + 1;
    int* elist  = cursor + NN;
    int* bsum   = elist + NEDGE;
    int* bbase  = bsum + SCAN_NBLK;

    hipMemsetAsync(d_out, 0, (size_t)out_size * sizeof(float), stream);
    hipMemsetAsync(ecnt, 0, NN * sizeof(int), stream);

    const dim3 blk(256);
    const dim3 gemm_grid((NN + BM - 1) / BM, HD / BN);   // (391, 2)
    const int  edge_grid = (NEDGE + 255) / 256;
    const int  node_grid = (NN + 3) / 4;

    // weight transposes (fp32 KxH -> bf16 HxK) + x conversion
    for (int L = 0; L < 7; ++L)
        transpose_w<<<dim3(Ks[L] / 32, HD / 32), blk, 0, stream>>>(Wsrc[L], WtB[L], Ks[L]);
    convert_x<<<(NN * 32 + 255) / 256, blk, 0, stream>>>(x, xb);

    // CSR build (reused by all 4 gconv layers)
    hist_tgt<<<edge_grid, blk, 0, stream>>>(edge, ecnt);
    block_sums<<<SCAN_NBLK, blk, 0, stream>>>(ecnt, bsum);
    scan_bsums<<<1, blk, 0, stream>>>(bsum, bbase, off);
    block_scan<<<SCAN_NBLK, blk, 0, stream>>>(ecnt, bbase, off, cursor);
    fill_elist<<<edge_grid, blk, 0, stream>>>(edge, cursor, elist);

    // pre0: xb(K=128) -> h
    gemm_bn_act<<<gemm_grid, blk, 0, stream>>>(xb, 128, WtB[0], 128, bi[0], bnp[0], ap[0], h, HD, NN);
    // pre1: h(K=256) -> act[:,1024:1280) (= out1)
    gemm_bn_act<<<gemm_grid, blk, 0, stream>>>(h, HD, WtB[1], 256, bi[1], bnp[1], ap[1], act + 1024, ACT_LD, NN);

    // gconv layers: input = act cols [1024-256L, 1280), K = 256*(L+1)
    for (int L = 0; L < 4; ++L) {
        const int in_off = 1024 - 256 * L;
        const int K      = 256 * (L + 1);
        gemm_bn_act<<<gemm_grid, blk, 0, stream>>>(act + in_off, ACT_LD, WtB[2 + L], K, bi[2 + L], bnp[2 + L], ap[2 + L], h, HD, NN);
        gather_nodes<<<node_grid, blk, 0, stream>>>(h, off, elist, act + (in_off - 256));
    }

    // post0: act(K=1280) -> h
    gemm_bn_act<<<gemm_grid, blk, 0, stream>>>(act, ACT_LD, WtB[6], 1280, bi[6], bnp[6], ap[6], h, HD, NN);
    // post1 + segment-sum -> d_out (64 floats)
    post1_segsum<<<(NN + 63) / 64, blk, 0, stream>>>(h, post1_W, post1_b, post1_bn, seg, (float*)d_out);
}